// Round 14
// baseline (138.460 us; speedup 1.0000x reference)
//
#include <hip/hip_runtime.h>

typedef short bf16x8 __attribute__((ext_vector_type(8)));
typedef float f32x4 __attribute__((ext_vector_type(4)));
typedef unsigned short u16;
typedef unsigned short u16x4 __attribute__((ext_vector_type(4)));
typedef unsigned short u16x8 __attribute__((ext_vector_type(8)));
typedef unsigned int u32;
typedef unsigned int u32x4 __attribute__((ext_vector_type(4)));

#define NB 4
#define LEN 1024
#define DM 1024
#define NH 16
#define HD 64

// 0.125 (1/sqrt(hd)) * log2(e): projections are emitted in exp2-domain
#define QSCALE 0.18033688011112043f

__device__ __forceinline__ u16 f2bf(float f) {
    union { float f; unsigned u; } v; v.f = f;
    return (u16)((v.u + 0x7fffu + ((v.u >> 16) & 1u)) >> 16);
}

__device__ __forceinline__ float bf2f(u16 x) {
    union { float f; unsigned u; } v; v.u = ((unsigned)x) << 16;
    return v.f;
}

__device__ __forceinline__ float exp2f_fast(float x) {
    float r; asm("v_exp_f32 %0, %1" : "=v"(r) : "v"(x)); return r;
}

__device__ __forceinline__ unsigned cvt_pk_bf16(float a, float b) {
    unsigned r; asm("v_cvt_pk_bf16_f32 %0, %1, %2" : "=v"(r) : "v"(a), "v"(b)); return r;
}

__device__ __forceinline__ f32x4 mfma16(bf16x8 a, bf16x8 b, f32x4 c) {
    return __builtin_amdgcn_mfma_f32_16x16x32_bf16(a, b, c, 0, 0, 0);
}

// async global->LDS, 16B per lane. LDS base must be wave-uniform (HW adds lane*16).
__device__ __forceinline__ void gload16(const void* g, void* l) {
    __builtin_amdgcn_global_load_lds(
        (const __attribute__((address_space(1))) unsigned int*)g,
        (__attribute__((address_space(3))) unsigned int*)l, 16, 0, 0);
}

// ---------------- prep: weight transposes only ----------------
__global__ void prep(const float* __restrict__ Wq, const float* __restrict__ Wkv,
                     u16* __restrict__ WqT, u16* __restrict__ WkvT) {
    __shared__ float tile[32][33];
    const int f = blockIdx.x;
    const int tid = threadIdx.x;
    const int x = f % 96, y = f / 96;
    const bool isQ = x < 32;
    const float* W = isQ ? Wq : Wkv;
    u16* WT = isQ ? WqT : WkvT;
    const int N = isQ ? 1024 : 2048;
    const int n0 = (isQ ? x : x - 32) * 32;
    const int k0 = y * 32;
    const int tx = tid & 31, ty = tid >> 5;
    #pragma unroll
    for (int j = 0; j < 4; j++) {
        int r = ty + j * 8;
        tile[r][tx] = W[(size_t)(k0 + r) * N + n0 + tx];
    }
    __syncthreads();
    #pragma unroll
    for (int j = 0; j < 4; j++) {
        int r = ty + j * 8;
        WT[(size_t)(n0 + r) * 1024 + k0 + tx] = f2bf(tile[tx][r]);
    }
}

// ---------------- unified GEMM (f32 A reg-staged) + r_proj + mask aux blocks ----------------
// fb < 768: XCD-chunked 128x128 GEMM. Q path writes only A1 (exp2-scaled).
// fb in [768, 1284): r_proj -> rbf (pre-swizzled rows, key=row&7).
// fb >= 1284: mask -> mb.
__global__ __launch_bounds__(256) void gemm_all(
    const float* __restrict__ qf, const float* __restrict__ kf32,
    const u16* __restrict__ WqT, const u16* __restrict__ WkvT,
    const float* __restrict__ rrb,
    const float* __restrict__ pos, const float* __restrict__ Wr,
    const int* __restrict__ msk,
    u16* __restrict__ A1,
    u16* __restrict__ khs, u16* __restrict__ vhsT,
    u16* __restrict__ rbf, float* __restrict__ mb)
{
    __shared__ u16 as[2][128][32];
    __shared__ u16 bs[2][128][32];

    const int fb = blockIdx.x;
    const int tid = threadIdx.x;

    if (fb >= 768) {
        if (fb < 1284) {
            // r = pos_embed @ Wr -> bf16, PRE-SWIZZLED rows (key = row&7), 2064 rows
            int idx = (fb - 768) * 256 + tid;
            if (idx < 2064 * 64) {
                int row = idx >> 6, col = idx & 63;
                float s = 0.f;
                if (row < 2048) {
                    #pragma unroll
                    for (int kk = 0; kk < 64; kk++) s += pos[row * 64 + kk] * Wr[kk * 64 + col];
                }
                const int csw = (((col >> 3) ^ (row & 7)) << 3) | (col & 7);
                rbf[(row << 6) | csw] = f2bf(s);
            }
        } else {
            int i = (fb - 1284) * 256 + tid;
            if (i < NB * LEN) mb[i] = msk[i] ? 0.f : -3.0e38f;
        }
        return;
    }

    // bijective XCD chunking over 768 gemm works: each XCD gets 96 consecutive
    const int wsw = ((fb & 7) * 96) + (fb >> 3);
    const int bx = wsw % 24;
    const bool isQ = bx < 8;
    const float* Af = isQ ? qf : kf32;
    const u16* BT  = isQ ? WqT : WkvT;
    const int n0 = (isQ ? bx : bx - 8) * 128;
    const int m0 = (wsw / 24) * 128;
    const int w = tid >> 6, lane = tid & 63, g = lane >> 4, c = lane & 15;
    const int wm = w >> 1, wn = w & 1;
    const int srow = lane >> 2, sj = lane & 3;
    const int arow = tid >> 1, ahalf = tid & 1;   // A staging: 2 threads/row

    const f32x4 fzero = {0.f, 0.f, 0.f, 0.f};
    f32x4 acc[4][4];
    #pragma unroll
    for (int i = 0; i < 4; i++)
        #pragma unroll
        for (int j = 0; j < 4; j++) acc[i][j] = fzero;

    float4 fa[4];
    const float* Abase = Af + (size_t)(m0 + arow) * 1024 + ahalf * 16;

    auto STAGE_LOAD = [&](int ks, int buf) {
        const int k0 = ks * 32;
        const float4* Ap = (const float4*)(Abase + k0);
        fa[0] = Ap[0]; fa[1] = Ap[1]; fa[2] = Ap[2]; fa[3] = Ap[3];
        #pragma unroll
        for (int i = 0; i < 2; i++) {
            const int rb = w * 32 + i * 16;
            const int rowB = rb + srow;
            gload16(BT + (size_t)(n0 + rowB) * 1024 + k0 + ((sj ^ (rowB & 3)) << 3),
                    &bs[buf][rb][0]);
        }
    };

    auto STAGE_WRITE = [&](int buf) {
        u32x4 d0, d1;
        d0[0] = cvt_pk_bf16(fa[0].x, fa[0].y); d0[1] = cvt_pk_bf16(fa[0].z, fa[0].w);
        d0[2] = cvt_pk_bf16(fa[1].x, fa[1].y); d0[3] = cvt_pk_bf16(fa[1].z, fa[1].w);
        d1[0] = cvt_pk_bf16(fa[2].x, fa[2].y); d1[1] = cvt_pk_bf16(fa[2].z, fa[2].w);
        d1[2] = cvt_pk_bf16(fa[3].x, fa[3].y); d1[3] = cvt_pk_bf16(fa[3].z, fa[3].w);
        const int j0 = 2 * ahalf, j1 = j0 + 1;
        *(u32x4*)&as[buf][arow][((j0 ^ (arow & 3)) << 3)] = d0;
        *(u32x4*)&as[buf][arow][((j1 ^ (arow & 3)) << 3)] = d1;
    };

    STAGE_LOAD(0, 0);
    STAGE_WRITE(0);
    __syncthreads();

    for (int ks = 0; ks < 32; ks++) {
        const int cur = ks & 1, nb = cur ^ 1;
        if (ks < 31) STAGE_LOAD(ks + 1, nb);

        bf16x8 af[4], bfr[4];
        #pragma unroll
        for (int i = 0; i < 4; i++) {
            const int row = wm * 64 + i * 16 + c;
            af[i] = *(const bf16x8*)&as[cur][row][(g ^ (row & 3)) << 3];
        }
        #pragma unroll
        for (int j = 0; j < 4; j++) {
            const int row = wn * 64 + j * 16 + c;
            bfr[j] = *(const bf16x8*)&bs[cur][row][(g ^ (row & 3)) << 3];
        }
        #pragma unroll
        for (int i = 0; i < 4; i++)
            #pragma unroll
            for (int j = 0; j < 4; j++)
                acc[i][j] = mfma16(af[i], bfr[j], acc[i][j]);

        if (ks < 31) STAGE_WRITE(nb);
        __syncthreads();
    }

    #pragma unroll
    for (int j = 0; j < 4; j++) {
        const int n = n0 + wn * 64 + j * 16 + c;
        float b1v = 0.f;
        if (isQ) b1v = rrb[n];
        #pragma unroll
        for (int i = 0; i < 4; i++) {
            const int l0 = m0 + wm * 64 + i * 16 + 4 * g;
            if (!isQ && n >= DM) {
                const int d = n & 63, hh = (n - DM) >> 6;
                const int bb = l0 >> 10, l = l0 & 1023;
                u16x4 o;
                #pragma unroll
                for (int r = 0; r < 4; r++) o[r] = f2bf(acc[i][j][r]);
                *(u16x4*)(vhsT + (((size_t)(bb * NH + hh)) * HD + d) * LEN + l) = o;
            } else {
                #pragma unroll
                for (int r = 0; r < 4; r++) {
                    const int row = l0 + r;
                    const int bb = row >> 10, l = row & 1023;
                    const float v = acc[i][j][r];
                    if (isQ) {
                        size_t idx = (((size_t)(bb * NH + (n >> 6))) * LEN + l) * HD + (n & 63);
                        A1[idx] = f2bf((v + b1v) * QSCALE);
                    } else {
                        const int d = n & 63;
                        const int dsw = (((d >> 3) ^ (l & 7)) << 3) | (d & 7);
                        size_t idx = (((size_t)(bb * NH + (n >> 6))) * LEN + l) * HD + dsw;
                        khs[idx] = f2bf(v);
                    }
                }
            }
        }
    }
}

// ---------------- fused rel-attention, v13 (unchanged): 224-row ring, R-carry, P-in-G ----------------
__global__ __launch_bounds__(512, 4) void attn_kernel(
    const u16* __restrict__ A1,
    const u16* __restrict__ khs, const u16* __restrict__ vhsT,
    const u16* __restrict__ rbf, const float* __restrict__ mbias,
    const float* __restrict__ rrb, const float* __restrict__ rwb,
    float* __restrict__ outp)
{
    __shared__ u16 kbuf[2][32][64];      // 8 KB, rows swizzled by key k&7
    __shared__ u16 rbuf[224][64];        // 28 KB rolling ring (slot = j mod 224), key j&7
    __shared__ u16 vbuf[2][4][64][8];    // 8 KB: [buf][kgroup][d][8 keys]
    __shared__ float biasl[1024];        // 4 KB
    __shared__ float gl[8][16][52];      // 26 KB band scores; P unioned into dwords [0,16)
    // total 75776 B -> 2 blocks/CU

    const int bh = blockIdx.x;
    const int b = bh >> 4, h = bh & 15;
    const int tid = threadIdx.x;
    const int w = tid >> 6, lane = tid & 63, g = lane >> 4, c = lane & 15;
    const int q0 = blockIdx.y * 128, q0w = q0 + w * 16;
    const int lrow8 = lane >> 3, lcol = lane & 7;
    const int kkey = (c + 1) & 7;

    const u16* Kbase = khs + (size_t)bh * LEN * HD;
    const u16* Vp = vhsT + (size_t)bh * HD * LEN;
    float* glw = &gl[w][0][0];
    u16* pw = (u16*)glw;

    // q-side fragments; a2f reconstructed from a1f + (rwb - rrb)*QSCALE
    const u16* A1p = A1 + ((size_t)bh * LEN + q0w) * HD;
    bf16x8 a1f[2], a2f[2];
    #pragma unroll
    for (int kf = 0; kf < 2; kf++)
        a1f[kf] = *(const bf16x8*)(A1p + c * HD + kf * 32 + g * 8);
    {
        const float* rrbp = rrb + h * HD;
        const float* rwbp = rwb + h * HD;
        #pragma unroll
        for (int kf = 0; kf < 2; kf++) {
            const int dbase = kf * 32 + g * 8;
            f32x4 rA0 = *(const f32x4*)(rrbp + dbase);
            f32x4 rA1 = *(const f32x4*)(rrbp + dbase + 4);
            f32x4 rB0 = *(const f32x4*)(rwbp + dbase);
            f32x4 rB1 = *(const f32x4*)(rwbp + dbase + 4);
            float a2v[8];
            #pragma unroll
            for (int e = 0; e < 4; e++) {
                a2v[e]     = bf2f((u16)a1f[kf][e])     + (rB0[e] - rA0[e]) * QSCALE;
                a2v[4 + e] = bf2f((u16)a1f[kf][4 + e]) + (rB1[e] - rA1[e]) * QSCALE;
            }
            union { u32 u[4]; bf16x8 v; } cv;
            cv.u[0] = cvt_pk_bf16(a2v[0], a2v[1]);
            cv.u[1] = cvt_pk_bf16(a2v[2], a2v[3]);
            cv.u[2] = cvt_pk_bf16(a2v[4], a2v[5]);
            cv.u[3] = cvt_pk_bf16(a2v[6], a2v[7]);
            a2f[kf] = cv.v;
        }
    }

    // ---- prologue staging ----
    const int js0 = LEN - q0 - 128;
    if (w < 4) {
        gload16(Kbase + (((size_t)(8 * w + lrow8)) << 6) + (lcol << 3), &kbuf[0][8 * w][0]);
        gload16(Vp + ((size_t)lane << 10) + 8 * w, &vbuf[0][w][0][0]);
    } else {
        gload16(mbias + b * LEN + (w - 4) * 256 + lane * 4, &biasl[(w - 4) * 256]);
    }
    #pragma unroll
    for (int i = 0; i < 3; i++) {
        const int row = js0 + 8 * (w + 8 * i);
        gload16(rbf + (((size_t)(row + lrow8)) << 6) + (lcol << 3), &rbuf[row % 224][0]);
    }
    __syncthreads();

    // initial R carry: mt0 fragment of tile 0
    bf16x8 RA[2], RB[2];
    int bs = (1009 - q0w) % 224;
    {
        int t = bs + c; if (t >= 224) t -= 224;
        #pragma unroll
        for (int kf = 0; kf < 2; kf++)
            RA[kf] = *(const bf16x8*)&rbuf[t][((4 * kf + g) ^ kkey) * 8];
    }

    const f32x4 fzero = {0.f, 0.f, 0.f, 0.f};
    f32x4 oacc[4];
    #pragma unroll
    for (int dt = 0; dt < 4; dt++) oacc[dt] = fzero;
    float mrow = -3.0e38f, lrow = 0.f;

    auto STEP = [&](int kt, bf16x8 (&Rold)[2], bf16x8 (&Rnew)[2]) {
        const int cur = kt & 1, nb = cur ^ 1;
        const int c0 = kt * 32;

        if (w < 4) {
            if (kt < 31) {
                const int c0n = c0 + 32;
                gload16(Kbase + (((size_t)(c0n + 8 * w + lrow8)) << 6) + (lcol << 3), &kbuf[nb][8 * w][0]);
                gload16(Vp + ((size_t)lane << 10) + c0n + 8 * w, &vbuf[nb][w][0][0]);
            }
        } else {
            if (kt < 30) {
                const int row0 = js0 + 192 + 32 * kt + 8 * (w - 4);
                gload16(rbf + (((size_t)(row0 + lrow8)) << 6) + (lcol << 3), &rbuf[row0 % 224][0]);
            }
        }

        bf16x8 Kf[2][2];
        #pragma unroll
        for (int ct = 0; ct < 2; ct++)
            #pragma unroll
            for (int kf = 0; kf < 2; kf++)
                Kf[ct][kf] = *(const bf16x8*)&kbuf[cur][16 * ct + c][((4 * kf + g) ^ (c & 7)) * 8];

        bf16x8 Rf1[2], Rf2[2];
        {
            int t = bs + 16 + c; if (t >= 224) t -= 224;
            #pragma unroll
            for (int kf = 0; kf < 2; kf++)
                Rf1[kf] = *(const bf16x8*)&rbuf[t][((4 * kf + g) ^ kkey) * 8];
        }
        {
            int t = bs + 32 + c; if (t >= 224) t -= 224;
            #pragma unroll
            for (int kf = 0; kf < 2; kf++) {
                Rf2[kf] = *(const bf16x8*)&rbuf[t][((4 * kf + g) ^ kkey) * 8];
                Rnew[kf] = Rf2[kf];
            }
        }

        __builtin_amdgcn_s_setprio(1);
        f32x4 s0 = fzero, s1 = fzero;
        s0 = mfma16(Kf[0][0], a1f[0], s0);
        s0 = mfma16(Kf[0][1], a1f[1], s0);
        s1 = mfma16(Kf[1][0], a1f[0], s1);
        s1 = mfma16(Kf[1][1], a1f[1], s1);
        f32x4 g0 = fzero, g1 = fzero, g2 = fzero;
        g0 = mfma16(Rold[0], a2f[0], g0);
        g0 = mfma16(Rold[1], a2f[1], g0);
        *(f32x4*)&glw[c * 52 + 4 * g] = g0;
        g1 = mfma16(Rf1[0], a2f[0], g1);
        g1 = mfma16(Rf1[1], a2f[1], g1);
        *(f32x4*)&glw[c * 52 + 16 + 4 * g] = g1;
        g2 = mfma16(Rf2[0], a2f[0], g2);
        g2 = mfma16(Rf2[1], a2f[1], g2);
        *(f32x4*)&glw[c * 52 + 32 + 4 * g] = g2;
        __builtin_amdgcn_s_setprio(0);

        const float* glq = &glw[c * 52];
        f32x4 bb0 = *(const f32x4*)&biasl[c0 + 4 * g];
        f32x4 bb1 = *(const f32x4*)&biasl[c0 + 16 + 4 * g];
        #pragma unroll
        for (int r = 0; r < 4; r++) {
            const int gidx = 4 * g + r + 15 - c;
            s0[r] += glq[gidx] + bb0[r];
            s1[r] += glq[gidx + 16] + bb1[r];
        }

        float t = fmaxf(fmaxf(fmaxf(s0[0], s0[1]), fmaxf(s0[2], s0[3])),
                        fmaxf(fmaxf(s1[0], s1[1]), fmaxf(s1[2], s1[3])));
        t = fmaxf(t, __shfl_xor(t, 16));
        t = fmaxf(t, __shfl_xor(t, 32));
        if (!__all(t <= mrow + 8.f)) {
            const float mnew = fmaxf(mrow, t);
            const float alpha = exp2f_fast(mrow - mnew);
            mrow = mnew;
            lrow *= alpha;
            #pragma unroll
            for (int dt = 0; dt < 4; dt++)
                #pragma unroll
                for (int r = 0; r < 4; r++) oacc[dt][r] *= alpha;
        }
        float p[8];
        float ps = 0.f;
        #pragma unroll
        for (int r = 0; r < 4; r++) {
            p[r] = exp2f_fast(s0[r] - mrow);
            p[4 + r] = exp2f_fast(s1[r] - mrow);
            ps += p[r] + p[4 + r];
        }
        lrow += ps;
        const unsigned d0 = cvt_pk_bf16(p[0], p[1]);
        const unsigned d1 = cvt_pk_bf16(p[2], p[3]);
        const unsigned d2 = cvt_pk_bf16(p[4], p[5]);
        const unsigned d3 = cvt_pk_bf16(p[6], p[7]);
        *(uint2*)&pw[c * 104 + 4 * g] = make_uint2(d0, d1);
        *(uint2*)&pw[c * 104 + 16 + 4 * g] = make_uint2(d2, d3);
        bf16x8 pbr = *(const bf16x8*)&pw[c * 104 + 8 * g];

        bf16x8 Vb[4];
        #pragma unroll
        for (int dt = 0; dt < 4; dt++)
            Vb[dt] = *(const bf16x8*)&vbuf[cur][g][16 * dt + c][0];
        __builtin_amdgcn_s_setprio(1);
        #pragma unroll
        for (int dt = 0; dt < 4; dt++)
            oacc[dt] = mfma16(Vb[dt], pbr, oacc[dt]);
        __builtin_amdgcn_s_setprio(0);

        bs += 32; if (bs >= 224) bs -= 224;
        __syncthreads();
    };

    for (int kt2 = 0; kt2 < 16; kt2++) {
        STEP(2 * kt2,     RA, RB);
        STEP(2 * kt2 + 1, RB, RA);
    }

    float sum = lrow;
    sum += __shfl_xor(sum, 16);
    sum += __shfl_xor(sum, 32);
    const float inv = sum > 0.f ? 1.0f / sum : 0.f;
    const int l = q0w + c;
    float* op = outp + ((size_t)b * LEN + l) * DM + h * HD;
    #pragma unroll
    for (int dt = 0; dt < 4; dt++) {
        f32x4 o;
        #pragma unroll
        for (int r = 0; r < 4; r++) o[r] = oacc[dt][r] * inv;
        *(f32x4*)(op + dt * 16 + 4 * g) = o;
    }
}

extern "C" void kernel_launch(void* const* d_in, const int* in_sizes, int n_in,
                              void* d_out, int out_size, void* d_ws, size_t ws_size,
                              hipStream_t stream) {
    const float* q   = (const float*)d_in[0];
    const float* k   = (const float*)d_in[1];
    const int*   msk = (const int*)d_in[2];
    const float* pos = (const float*)d_in[3];
    const float* Wq  = (const float*)d_in[4];
    const float* Wkv = (const float*)d_in[5];
    const float* Wr  = (const float*)d_in[6];
    const float* rrb = (const float*)d_in[7];
    const float* rwb = (const float*)d_in[8];
    float* outp = (float*)d_out;
    char* ws = (char*)d_ws;

    u16* WqT  = (u16*)(ws + 16777216);       // 2 MB
    u16* WkvT = (u16*)(ws + 18874368);       // 4 MB
    u16* rbf  = (u16*)(ws + 23068672);       // 2064*64*2 (swizzled key row&7)
    u16* A1   = (u16*)(ws + 23332864);       // 8 MB (exp2-scaled)
    u16* khs  = (u16*)(ws + 40110080);       // 8 MB (swizzled key l&7)
    u16* vhsT = (u16*)(ws + 48498688);       // 8 MB
    float* mb = (float*)(ws + 56887296);     // 16 KB mask bias

    prep<<<3072, 256, 0, stream>>>(Wq, Wkv, WqT, WkvT);
    gemm_all<<<1300, 256, 0, stream>>>(q, k, WqT, WkvT, rrb, pos, Wr, msk,
                                       A1, khs, vhsT, rbf, mb);
    attn_kernel<<<dim3(64, 8), 512, 0, stream>>>(A1, khs, vhsT, rbf, mb, rrb, rwb, outp);
}

// Round 15
// 113.644 us; speedup vs baseline: 1.2184x; 1.2184x over previous
//
#include <hip/hip_runtime.h>

typedef short bf16x8 __attribute__((ext_vector_type(8)));
typedef float f32x4 __attribute__((ext_vector_type(4)));
typedef unsigned short u16;
typedef unsigned short u16x4 __attribute__((ext_vector_type(4)));
typedef unsigned short u16x8 __attribute__((ext_vector_type(8)));
typedef unsigned int u32;

#define NB 4
#define LEN 1024
#define DM 1024
#define NH 16
#define HD 64

// 0.125 (1/sqrt(hd)) * log2(e): projections are emitted in exp2-domain
#define QSCALE 0.18033688011112043f

__device__ __forceinline__ u16 f2bf(float f) {
    union { float f; unsigned u; } v; v.f = f;
    return (u16)((v.u + 0x7fffu + ((v.u >> 16) & 1u)) >> 16);
}

__device__ __forceinline__ float bf2f(u16 x) {
    union { float f; unsigned u; } v; v.u = ((unsigned)x) << 16;
    return v.f;
}

__device__ __forceinline__ float exp2f_fast(float x) {
    float r; asm("v_exp_f32 %0, %1" : "=v"(r) : "v"(x)); return r;
}

__device__ __forceinline__ unsigned cvt_pk_bf16(float a, float b) {
    unsigned r; asm("v_cvt_pk_bf16_f32 %0, %1, %2" : "=v"(r) : "v"(a), "v"(b)); return r;
}

__device__ __forceinline__ f32x4 mfma16(bf16x8 a, bf16x8 b, f32x4 c) {
    return __builtin_amdgcn_mfma_f32_16x16x32_bf16(a, b, c, 0, 0, 0);
}

// async global->LDS, 16B per lane. LDS base must be wave-uniform (HW adds lane*16).
__device__ __forceinline__ void gload16(const void* g, void* l) {
    __builtin_amdgcn_global_load_lds(
        (const __attribute__((address_space(1))) unsigned int*)g,
        (__attribute__((address_space(3))) unsigned int*)l, 16, 0, 0);
}

// ---------------- fused prep: weight transposes + r-proj + mask + q/k casts ----------------
__global__ void prep(const float* __restrict__ q, const float* __restrict__ k,
                     const int* __restrict__ msk,
                     const float* __restrict__ Wq, const float* __restrict__ Wkv,
                     const float* __restrict__ pos, const float* __restrict__ Wr,
                     u16* __restrict__ qbf, u16* __restrict__ kbf,
                     u16* __restrict__ WqT, u16* __restrict__ WkvT,
                     u16* __restrict__ rbf, float* __restrict__ mb) {
    __shared__ float tile[32][33];
    const int f = blockIdx.x;
    const int tid = threadIdx.x;
    if (f < 3072) {
        // transpose + cast weights: W[K][N] -> WT[N][K] bf16
        const int x = f % 96, y = f / 96;
        const bool isQ = x < 32;
        const float* W = isQ ? Wq : Wkv;
        u16* WT = isQ ? WqT : WkvT;
        const int N = isQ ? 1024 : 2048;
        const int n0 = (isQ ? x : x - 32) * 32;
        const int k0 = y * 32;
        const int tx = tid & 31, ty = tid >> 5;
        #pragma unroll
        for (int j = 0; j < 4; j++) {
            int r = ty + j * 8;
            tile[r][tx] = W[(size_t)(k0 + r) * N + n0 + tx];
        }
        __syncthreads();
        #pragma unroll
        for (int j = 0; j < 4; j++) {
            int r = ty + j * 8;
            WT[(size_t)(n0 + r) * 1024 + k0 + tx] = f2bf(tile[tx][r]);
        }
    } else if (f < 3588) {
        // r = pos_embed @ Wr -> bf16, PRE-SWIZZLED rows (key = row&7), 2064 rows
        int idx = (f - 3072) * 256 + tid;
        if (idx < 2064 * 64) {
            int row = idx >> 6, col = idx & 63;
            float s = 0.f;
            if (row < 2048) {
                #pragma unroll
                for (int kk = 0; kk < 64; kk++) s += pos[row * 64 + kk] * Wr[kk * 64 + col];
            }
            const int csw = (((col >> 3) ^ (row & 7)) << 3) | (col & 7);
            rbf[(row << 6) | csw] = f2bf(s);
        }
    } else if (f < 3604) {
        int i = (f - 3588) * 256 + tid;
        if (i < NB * LEN) mb[i] = msk[i] ? 0.f : -3.0e38f;
    } else {
        // cast q,k fp32 -> bf16 (float4 per thread)
        int idx = (f - 3604) * 256 + tid;
        if (idx < 1048576) {
            float4 v = ((const float4*)q)[idx];
            u16x4 o;
            o[0] = f2bf(v.x); o[1] = f2bf(v.y); o[2] = f2bf(v.z); o[3] = f2bf(v.w);
            ((u16x4*)qbf)[idx] = o;
        } else if (idx < 2097152) {
            int i = idx - 1048576;
            float4 v = ((const float4*)k)[i];
            u16x4 o;
            o[0] = f2bf(v.x); o[1] = f2bf(v.y); o[2] = f2bf(v.z); o[3] = f2bf(v.w);
            ((u16x4*)kbf)[i] = o;
        }
    }
}

// ---------------- unified 128x128 projection GEMM (Q + KV), XCD-chunked ----------------
// Q path writes ONLY A1 (A2 reconstructed in attn from A1 + (rwb-rrb)*QSCALE).
__global__ __launch_bounds__(256) void gemm_all(
    const u16* __restrict__ qbf, const u16* __restrict__ kbf,
    const u16* __restrict__ WqT, const u16* __restrict__ WkvT,
    const float* __restrict__ rrb,
    u16* __restrict__ A1,
    u16* __restrict__ khs, u16* __restrict__ vhsT)
{
    __shared__ u16 as[2][128][32];
    __shared__ u16 bs[2][128][32];

    const int fb = blockIdx.x;
    const int wsw = ((fb & 7) * 96) + (fb >> 3);
    const int bx = wsw % 24;
    const bool isQ = bx < 8;
    const u16* Abf = isQ ? qbf : kbf;
    const u16* BT  = isQ ? WqT : WkvT;
    const int n0 = (isQ ? bx : bx - 8) * 128;
    const int m0 = (wsw / 24) * 128;
    const int tid = threadIdx.x;
    const int w = tid >> 6, lane = tid & 63, g = lane >> 4, c = lane & 15;
    const int wm = w >> 1, wn = w & 1;
    const int srow = lane >> 2, sj = lane & 3;

    const f32x4 fzero = {0.f, 0.f, 0.f, 0.f};
    f32x4 acc[4][4];
    #pragma unroll
    for (int i = 0; i < 4; i++)
        #pragma unroll
        for (int j = 0; j < 4; j++) acc[i][j] = fzero;

    auto STAGE = [&](int buf, int ks) {
        const int k0 = ks * 32;
        #pragma unroll
        for (int i = 0; i < 2; i++) {
            const int rb = w * 32 + i * 16;
            const int rowA = rb + srow;
            gload16(Abf + (size_t)(m0 + rowA) * 1024 + k0 + ((sj ^ (rowA & 3)) << 3),
                    &as[buf][rb][0]);
            gload16(BT + (size_t)(n0 + rowA) * 1024 + k0 + ((sj ^ (rowA & 3)) << 3),
                    &bs[buf][rb][0]);
        }
    };

    STAGE(0, 0);
    __syncthreads();

    for (int ks = 0; ks < 32; ks++) {
        const int cur = ks & 1, nb = cur ^ 1;
        if (ks < 31) STAGE(nb, ks + 1);

        bf16x8 af[4], bfr[4];
        #pragma unroll
        for (int i = 0; i < 4; i++) {
            const int row = wm * 64 + i * 16 + c;
            af[i] = *(const bf16x8*)&as[cur][row][(g ^ (row & 3)) << 3];
        }
        #pragma unroll
        for (int j = 0; j < 4; j++) {
            const int row = wn * 64 + j * 16 + c;
            bfr[j] = *(const bf16x8*)&bs[cur][row][(g ^ (row & 3)) << 3];
        }
        #pragma unroll
        for (int i = 0; i < 4; i++)
            #pragma unroll
            for (int j = 0; j < 4; j++)
                acc[i][j] = mfma16(af[i], bfr[j], acc[i][j]);

        __syncthreads();
    }

    #pragma unroll
    for (int j = 0; j < 4; j++) {
        const int n = n0 + wn * 64 + j * 16 + c;
        float b1v = 0.f;
        if (isQ) b1v = rrb[n];
        #pragma unroll
        for (int i = 0; i < 4; i++) {
            const int l0 = m0 + wm * 64 + i * 16 + 4 * g;
            if (!isQ && n >= DM) {
                const int d = n & 63, hh = (n - DM) >> 6;
                const int bb = l0 >> 10, l = l0 & 1023;
                u16x4 o;
                #pragma unroll
                for (int r = 0; r < 4; r++) o[r] = f2bf(acc[i][j][r]);
                *(u16x4*)(vhsT + (((size_t)(bb * NH + hh)) * HD + d) * LEN + l) = o;
            } else {
                #pragma unroll
                for (int r = 0; r < 4; r++) {
                    const int row = l0 + r;
                    const int bb = row >> 10, l = row & 1023;
                    const float v = acc[i][j][r];
                    if (isQ) {
                        size_t idx = (((size_t)(bb * NH + (n >> 6))) * LEN + l) * HD + (n & 63);
                        A1[idx] = f2bf((v + b1v) * QSCALE);
                    } else {
                        const int d = n & 63;
                        const int dsw = (((d >> 3) ^ (l & 7)) << 3) | (d & 7);
                        size_t idx = (((size_t)(bb * NH + (n >> 6))) * LEN + l) * HD + dsw;
                        khs[idx] = f2bf(v);
                    }
                }
            }
        }
    }
}

// ---------------- fused rel-attention, v13: 224-row ring (2-ahead), R-carry, P-in-G ----------------
// grid (64, 8), 512 threads, 8 waves x 16 q-rows. KVBLK=32.
// LDS 75776 B -> 2 blocks/CU. R staged TWO tiles ahead -> register carry of mt2->mt0 is race-free.
// P tile lives in gl rows (dwords [0,16)) after the gather has consumed them (same-lane, same-wave).
__global__ __launch_bounds__(512, 4) void attn_kernel(
    const u16* __restrict__ A1,
    const u16* __restrict__ khs, const u16* __restrict__ vhsT,
    const u16* __restrict__ rbf, const float* __restrict__ mbias,
    const float* __restrict__ rrb, const float* __restrict__ rwb,
    float* __restrict__ outp)
{
    __shared__ u16 kbuf[2][32][64];      // 8 KB, rows swizzled by key k&7
    __shared__ u16 rbuf[224][64];        // 28 KB rolling ring (slot = j mod 224), key j&7
    __shared__ u16 vbuf[2][4][64][8];    // 8 KB: [buf][kgroup][d][8 keys]
    __shared__ float biasl[1024];        // 4 KB
    __shared__ float gl[8][16][52];      // 26 KB band scores; P unioned into dwords [0,16)
    // total 75776 B -> 2 blocks/CU

    const int bh = blockIdx.x;
    const int b = bh >> 4, h = bh & 15;
    const int tid = threadIdx.x;
    const int w = tid >> 6, lane = tid & 63, g = lane >> 4, c = lane & 15;
    const int q0 = blockIdx.y * 128, q0w = q0 + w * 16;
    const int lrow8 = lane >> 3, lcol = lane & 7;
    const int kkey = (c + 1) & 7;

    const u16* Kbase = khs + (size_t)bh * LEN * HD;
    const u16* Vp = vhsT + (size_t)bh * HD * LEN;
    float* glw = &gl[w][0][0];
    u16* pw = (u16*)glw;

    // q-side fragments; a2f reconstructed from a1f + (rwb - rrb)*QSCALE
    const u16* A1p = A1 + ((size_t)bh * LEN + q0w) * HD;
    bf16x8 a1f[2], a2f[2];
    #pragma unroll
    for (int kf = 0; kf < 2; kf++)
        a1f[kf] = *(const bf16x8*)(A1p + c * HD + kf * 32 + g * 8);
    {
        const float* rrbp = rrb + h * HD;
        const float* rwbp = rwb + h * HD;
        #pragma unroll
        for (int kf = 0; kf < 2; kf++) {
            const int dbase = kf * 32 + g * 8;
            f32x4 rA0 = *(const f32x4*)(rrbp + dbase);
            f32x4 rA1 = *(const f32x4*)(rrbp + dbase + 4);
            f32x4 rB0 = *(const f32x4*)(rwbp + dbase);
            f32x4 rB1 = *(const f32x4*)(rwbp + dbase + 4);
            float a2v[8];
            #pragma unroll
            for (int e = 0; e < 4; e++) {
                a2v[e]     = bf2f((u16)a1f[kf][e])     + (rB0[e] - rA0[e]) * QSCALE;
                a2v[4 + e] = bf2f((u16)a1f[kf][4 + e]) + (rB1[e] - rA1[e]) * QSCALE;
            }
            union { u32 u[4]; bf16x8 v; } cv;
            cv.u[0] = cvt_pk_bf16(a2v[0], a2v[1]);
            cv.u[1] = cvt_pk_bf16(a2v[2], a2v[3]);
            cv.u[2] = cvt_pk_bf16(a2v[4], a2v[5]);
            cv.u[3] = cvt_pk_bf16(a2v[6], a2v[7]);
            a2f[kf] = cv.v;
        }
    }

    // ---- prologue staging: K(0)/V(0) by waves 0-3; bias by waves 4-7; ring 192 rows all waves ----
    const int js0 = LEN - q0 - 128;                  // >= 0, mult of 32
    if (w < 4) {
        gload16(Kbase + (((size_t)(8 * w + lrow8)) << 6) + (lcol << 3), &kbuf[0][8 * w][0]);
        gload16(Vp + ((size_t)lane << 10) + 8 * w, &vbuf[0][w][0][0]);
    } else {
        gload16(mbias + b * LEN + (w - 4) * 256 + lane * 4, &biasl[(w - 4) * 256]);
    }
    #pragma unroll
    for (int i = 0; i < 3; i++) {
        const int row = js0 + 8 * (w + 8 * i);       // groups 0..23 -> rows js0..js0+191
        gload16(rbf + (((size_t)(row + lrow8)) << 6) + (lcol << 3), &rbuf[row % 224][0]);
    }
    __syncthreads();

    // initial R carry: mt0 fragment of tile 0
    bf16x8 RA[2], RB[2];
    int bs = (1009 - q0w) % 224;                     // band base slot for tile 0
    {
        int t = bs + c; if (t >= 224) t -= 224;
        #pragma unroll
        for (int kf = 0; kf < 2; kf++)
            RA[kf] = *(const bf16x8*)&rbuf[t][((4 * kf + g) ^ kkey) * 8];
    }

    const f32x4 fzero = {0.f, 0.f, 0.f, 0.f};
    f32x4 oacc[4];
    #pragma unroll
    for (int dt = 0; dt < 4; dt++) oacc[dt] = fzero;
    float mrow = -3.0e38f, lrow = 0.f;

    auto STEP = [&](int kt, bf16x8 (&Rold)[2], bf16x8 (&Rnew)[2]) {
        const int cur = kt & 1, nb = cur ^ 1;
        const int c0 = kt * 32;

        // ---- staging: K/V one tile ahead (waves 0-3); ring rows TWO tiles ahead (waves 4-7) ----
        if (w < 4) {
            if (kt < 31) {
                const int c0n = c0 + 32;
                gload16(Kbase + (((size_t)(c0n + 8 * w + lrow8)) << 6) + (lcol << 3), &kbuf[nb][8 * w][0]);
                gload16(Vp + ((size_t)lane << 10) + c0n + 8 * w, &vbuf[nb][w][0][0]);
            }
        } else {
            if (kt < 30) {
                const int row0 = js0 + 192 + 32 * kt + 8 * (w - 4);
                gload16(rbf + (((size_t)(row0 + lrow8)) << 6) + (lcol << 3), &rbuf[row0 % 224][0]);
            }
        }

        // ---- K fragments ----
        bf16x8 Kf[2][2];
        #pragma unroll
        for (int ct = 0; ct < 2; ct++)
            #pragma unroll
            for (int kf = 0; kf < 2; kf++)
                Kf[ct][kf] = *(const bf16x8*)&kbuf[cur][16 * ct + c][((4 * kf + g) ^ (c & 7)) * 8];

        // ---- R fragments: mt0 carried; read mt1, mt2 (mt2 -> next carry) ----
        bf16x8 Rf1[2], Rf2[2];
        {
            int t = bs + 16 + c; if (t >= 224) t -= 224;
            #pragma unroll
            for (int kf = 0; kf < 2; kf++)
                Rf1[kf] = *(const bf16x8*)&rbuf[t][((4 * kf + g) ^ kkey) * 8];
        }
        {
            int t = bs + 32 + c; if (t >= 224) t -= 224;
            #pragma unroll
            for (int kf = 0; kf < 2; kf++) {
                Rf2[kf] = *(const bf16x8*)&rbuf[t][((4 * kf + g) ^ kkey) * 8];
                Rnew[kf] = Rf2[kf];
            }
        }

        // ---- AC + band G MFMA cluster ----
        __builtin_amdgcn_s_setprio(1);
        f32x4 s0 = fzero, s1 = fzero;
        s0 = mfma16(Kf[0][0], a1f[0], s0);
        s0 = mfma16(Kf[0][1], a1f[1], s0);
        s1 = mfma16(Kf[1][0], a1f[0], s1);
        s1 = mfma16(Kf[1][1], a1f[1], s1);
        f32x4 g0 = fzero, g1 = fzero, g2 = fzero;
        g0 = mfma16(Rold[0], a2f[0], g0);
        g0 = mfma16(Rold[1], a2f[1], g0);
        *(f32x4*)&glw[c * 52 + 4 * g] = g0;
        g1 = mfma16(Rf1[0], a2f[0], g1);
        g1 = mfma16(Rf1[1], a2f[1], g1);
        *(f32x4*)&glw[c * 52 + 16 + 4 * g] = g1;
        g2 = mfma16(Rf2[0], a2f[0], g2);
        g2 = mfma16(Rf2[1], a2f[1], g2);
        *(f32x4*)&glw[c * 52 + 32 + 4 * g] = g2;
        __builtin_amdgcn_s_setprio(0);

        // ---- gather band + bias: s[ct][r] += G[c][16ct + 4g+r+15-c] ----
        const float* glq = &glw[c * 52];
        f32x4 bb0 = *(const f32x4*)&biasl[c0 + 4 * g];
        f32x4 bb1 = *(const f32x4*)&biasl[c0 + 16 + 4 * g];
        #pragma unroll
        for (int r = 0; r < 4; r++) {
            const int gidx = 4 * g + r + 15 - c;
            s0[r] += glq[gidx] + bb0[r];
            s1[r] += glq[gidx + 16] + bb1[r];
        }

        // ---- online softmax (exp2 domain, defer-max) ----
        float t = fmaxf(fmaxf(fmaxf(s0[0], s0[1]), fmaxf(s0[2], s0[3])),
                        fmaxf(fmaxf(s1[0], s1[1]), fmaxf(s1[2], s1[3])));
        t = fmaxf(t, __shfl_xor(t, 16));
        t = fmaxf(t, __shfl_xor(t, 32));
        if (!__all(t <= mrow + 8.f)) {
            const float mnew = fmaxf(mrow, t);
            const float alpha = exp2f_fast(mrow - mnew);
            mrow = mnew;
            lrow *= alpha;
            #pragma unroll
            for (int dt = 0; dt < 4; dt++)
                #pragma unroll
                for (int r = 0; r < 4; r++) oacc[dt][r] *= alpha;
        }
        float p[8];
        float ps = 0.f;
        #pragma unroll
        for (int r = 0; r < 4; r++) {
            p[r] = exp2f_fast(s0[r] - mrow);
            p[4 + r] = exp2f_fast(s1[r] - mrow);
            ps += p[r] + p[4 + r];
        }
        lrow += ps;
        // ---- P into gl rows (each lane owns row c for both gather-read and P-write) ----
        const unsigned d0 = cvt_pk_bf16(p[0], p[1]);
        const unsigned d1 = cvt_pk_bf16(p[2], p[3]);
        const unsigned d2 = cvt_pk_bf16(p[4], p[5]);
        const unsigned d3 = cvt_pk_bf16(p[6], p[7]);
        *(uint2*)&pw[c * 104 + 4 * g] = make_uint2(d0, d1);
        *(uint2*)&pw[c * 104 + 16 + 4 * g] = make_uint2(d2, d3);
        bf16x8 pbr = *(const bf16x8*)&pw[c * 104 + 8 * g];

        // ---- PV ----
        bf16x8 Vb[4];
        #pragma unroll
        for (int dt = 0; dt < 4; dt++)
            Vb[dt] = *(const bf16x8*)&vbuf[cur][g][16 * dt + c][0];
        __builtin_amdgcn_s_setprio(1);
        #pragma unroll
        for (int dt = 0; dt < 4; dt++)
            oacc[dt] = mfma16(Vb[dt], pbr, oacc[dt]);
        __builtin_amdgcn_s_setprio(0);

        bs += 32; if (bs >= 224) bs -= 224;
        __syncthreads();
    };

    for (int kt2 = 0; kt2 < 16; kt2++) {
        STEP(2 * kt2,     RA, RB);
        STEP(2 * kt2 + 1, RB, RA);
    }

    // ---- epilogue ----
    float sum = lrow;
    sum += __shfl_xor(sum, 16);
    sum += __shfl_xor(sum, 32);
    const float inv = sum > 0.f ? 1.0f / sum : 0.f;
    const int l = q0w + c;
    float* op = outp + ((size_t)b * LEN + l) * DM + h * HD;
    #pragma unroll
    for (int dt = 0; dt < 4; dt++) {
        f32x4 o;
        #pragma unroll
        for (int r = 0; r < 4; r++) o[r] = oacc[dt][r] * inv;
        *(f32x4*)(op + dt * 16 + 4 * g) = o;
    }
}

extern "C" void kernel_launch(void* const* d_in, const int* in_sizes, int n_in,
                              void* d_out, int out_size, void* d_ws, size_t ws_size,
                              hipStream_t stream) {
    const float* q   = (const float*)d_in[0];
    const float* k   = (const float*)d_in[1];
    const int*   msk = (const int*)d_in[2];
    const float* pos = (const float*)d_in[3];
    const float* Wq  = (const float*)d_in[4];
    const float* Wkv = (const float*)d_in[5];
    const float* Wr  = (const float*)d_in[6];
    const float* rrb = (const float*)d_in[7];
    const float* rwb = (const float*)d_in[8];
    float* outp = (float*)d_out;
    char* ws = (char*)d_ws;

    u16* qbf  = (u16*)(ws + 0);              // 8 MB
    u16* kbf  = (u16*)(ws + 8388608);        // 8 MB
    u16* WqT  = (u16*)(ws + 16777216);       // 2 MB
    u16* WkvT = (u16*)(ws + 18874368);       // 4 MB
    u16* rbf  = (u16*)(ws + 23068672);       // 2064*64*2 (swizzled key row&7)
    u16* A1   = (u16*)(ws + 23332864);       // 8 MB (exp2-scaled)
    u16* khs  = (u16*)(ws + 40110080);       // 8 MB (swizzled key l&7)
    u16* vhsT = (u16*)(ws + 48498688);       // 8 MB
    float* mb = (float*)(ws + 56887296);     // 16 KB mask bias

    prep<<<11796, 256, 0, stream>>>(q, k, msk, Wq, Wkv, pos, Wr, qbf, kbf, WqT, WkvT, rbf, mb);
    gemm_all<<<768, 256, 0, stream>>>(qbf, kbf, WqT, WkvT, rrb, A1, khs, vhsT);
    attn_kernel<<<dim3(64, 8), 512, 0, stream>>>(A1, khs, vhsT, rbf, mb, rrb, rwb, outp);
}

// Round 16
// 111.731 us; speedup vs baseline: 1.2392x; 1.0171x over previous
//
#include <hip/hip_runtime.h>

typedef short bf16x8 __attribute__((ext_vector_type(8)));
typedef float f32x4 __attribute__((ext_vector_type(4)));
typedef unsigned short u16;
typedef unsigned short u16x4 __attribute__((ext_vector_type(4)));
typedef unsigned short u16x8 __attribute__((ext_vector_type(8)));
typedef unsigned int u32;

#define NB 4
#define LEN 1024
#define DM 1024
#define NH 16
#define HD 64

// 0.125 (1/sqrt(hd)) * log2(e): projections are emitted in exp2-domain
#define QSCALE 0.18033688011112043f

__device__ __forceinline__ u16 f2bf(float f) {
    union { float f; unsigned u; } v; v.f = f;
    return (u16)((v.u + 0x7fffu + ((v.u >> 16) & 1u)) >> 16);
}

__device__ __forceinline__ float bf2f(u16 x) {
    union { float f; unsigned u; } v; v.u = ((unsigned)x) << 16;
    return v.f;
}

__device__ __forceinline__ float exp2f_fast(float x) {
    float r; asm("v_exp_f32 %0, %1" : "=v"(r) : "v"(x)); return r;
}

__device__ __forceinline__ unsigned cvt_pk_bf16(float a, float b) {
    unsigned r; asm("v_cvt_pk_bf16_f32 %0, %1, %2" : "=v"(r) : "v"(a), "v"(b)); return r;
}

__device__ __forceinline__ f32x4 mfma16(bf16x8 a, bf16x8 b, f32x4 c) {
    return __builtin_amdgcn_mfma_f32_16x16x32_bf16(a, b, c, 0, 0, 0);
}

// async global->LDS, 16B per lane. LDS base must be wave-uniform (HW adds lane*16).
__device__ __forceinline__ void gload16(const void* g, void* l) {
    __builtin_amdgcn_global_load_lds(
        (const __attribute__((address_space(1))) unsigned int*)g,
        (__attribute__((address_space(3))) unsigned int*)l, 16, 0, 0);
}

// ---------------- fused prep: weight transposes + r-proj + mask + q/k casts ----------------
__global__ void prep(const float* __restrict__ q, const float* __restrict__ k,
                     const int* __restrict__ msk,
                     const float* __restrict__ Wq, const float* __restrict__ Wkv,
                     const float* __restrict__ pos, const float* __restrict__ Wr,
                     u16* __restrict__ qbf, u16* __restrict__ kbf,
                     u16* __restrict__ WqT, u16* __restrict__ WkvT,
                     u16* __restrict__ rbf, float* __restrict__ mb) {
    __shared__ float tile[32][33];
    const int f = blockIdx.x;
    const int tid = threadIdx.x;
    if (f < 3072) {
        // transpose + cast weights: W[K][N] -> WT[N][K] bf16
        const int x = f % 96, y = f / 96;
        const bool isQ = x < 32;
        const float* W = isQ ? Wq : Wkv;
        u16* WT = isQ ? WqT : WkvT;
        const int N = isQ ? 1024 : 2048;
        const int n0 = (isQ ? x : x - 32) * 32;
        const int k0 = y * 32;
        const int tx = tid & 31, ty = tid >> 5;
        #pragma unroll
        for (int j = 0; j < 4; j++) {
            int r = ty + j * 8;
            tile[r][tx] = W[(size_t)(k0 + r) * N + n0 + tx];
        }
        __syncthreads();
        #pragma unroll
        for (int j = 0; j < 4; j++) {
            int r = ty + j * 8;
            WT[(size_t)(n0 + r) * 1024 + k0 + tx] = f2bf(tile[tx][r]);
        }
    } else if (f < 3588) {
        // r = pos_embed @ Wr -> bf16, PRE-SWIZZLED rows (key = row&7), 2064 rows
        int idx = (f - 3072) * 256 + tid;
        if (idx < 2064 * 64) {
            int row = idx >> 6, col = idx & 63;
            float s = 0.f;
            if (row < 2048) {
                #pragma unroll
                for (int kk = 0; kk < 64; kk++) s += pos[row * 64 + kk] * Wr[kk * 64 + col];
            }
            const int csw = (((col >> 3) ^ (row & 7)) << 3) | (col & 7);
            rbf[(row << 6) | csw] = f2bf(s);
        }
    } else if (f < 3604) {
        int i = (f - 3588) * 256 + tid;
        if (i < NB * LEN) mb[i] = msk[i] ? 0.f : -3.0e38f;
    } else {
        // cast q,k fp32 -> bf16 (float4 per thread)
        int idx = (f - 3604) * 256 + tid;
        if (idx < 1048576) {
            float4 v = ((const float4*)q)[idx];
            u16x4 o;
            o[0] = f2bf(v.x); o[1] = f2bf(v.y); o[2] = f2bf(v.z); o[3] = f2bf(v.w);
            ((u16x4*)qbf)[idx] = o;
        } else if (idx < 2097152) {
            int i = idx - 1048576;
            float4 v = ((const float4*)k)[i];
            u16x4 o;
            o[0] = f2bf(v.x); o[1] = f2bf(v.y); o[2] = f2bf(v.z); o[3] = f2bf(v.w);
            ((u16x4*)kbf)[i] = o;
        }
    }
}

// ---------------- unified 128x128 projection GEMM (Q + KV), XCD-chunked ----------------
// Q path writes ONLY A1 (A2 reconstructed in attn from A1 + (rwb-rrb)*QSCALE).
__global__ __launch_bounds__(256) void gemm_all(
    const u16* __restrict__ qbf, const u16* __restrict__ kbf,
    const u16* __restrict__ WqT, const u16* __restrict__ WkvT,
    const float* __restrict__ rrb,
    u16* __restrict__ A1,
    u16* __restrict__ khs, u16* __restrict__ vhsT)
{
    __shared__ u16 as[2][128][32];
    __shared__ u16 bs[2][128][32];

    const int fb = blockIdx.x;
    const int wsw = ((fb & 7) * 96) + (fb >> 3);
    const int bx = wsw % 24;
    const bool isQ = bx < 8;
    const u16* Abf = isQ ? qbf : kbf;
    const u16* BT  = isQ ? WqT : WkvT;
    const int n0 = (isQ ? bx : bx - 8) * 128;
    const int m0 = (wsw / 24) * 128;
    const int tid = threadIdx.x;
    const int w = tid >> 6, lane = tid & 63, g = lane >> 4, c = lane & 15;
    const int wm = w >> 1, wn = w & 1;
    const int srow = lane >> 2, sj = lane & 3;

    const f32x4 fzero = {0.f, 0.f, 0.f, 0.f};
    f32x4 acc[4][4];
    #pragma unroll
    for (int i = 0; i < 4; i++)
        #pragma unroll
        for (int j = 0; j < 4; j++) acc[i][j] = fzero;

    auto STAGE = [&](int buf, int ks) {
        const int k0 = ks * 32;
        #pragma unroll
        for (int i = 0; i < 2; i++) {
            const int rb = w * 32 + i * 16;
            const int rowA = rb + srow;
            gload16(Abf + (size_t)(m0 + rowA) * 1024 + k0 + ((sj ^ (rowA & 3)) << 3),
                    &as[buf][rb][0]);
            gload16(BT + (size_t)(n0 + rowA) * 1024 + k0 + ((sj ^ (rowA & 3)) << 3),
                    &bs[buf][rb][0]);
        }
    };

    STAGE(0, 0);
    __syncthreads();

    for (int ks = 0; ks < 32; ks++) {
        const int cur = ks & 1, nb = cur ^ 1;
        if (ks < 31) STAGE(nb, ks + 1);

        bf16x8 af[4], bfr[4];
        #pragma unroll
        for (int i = 0; i < 4; i++) {
            const int row = wm * 64 + i * 16 + c;
            af[i] = *(const bf16x8*)&as[cur][row][(g ^ (row & 3)) << 3];
        }
        #pragma unroll
        for (int j = 0; j < 4; j++) {
            const int row = wn * 64 + j * 16 + c;
            bfr[j] = *(const bf16x8*)&bs[cur][row][(g ^ (row & 3)) << 3];
        }
        #pragma unroll
        for (int i = 0; i < 4; i++)
            #pragma unroll
            for (int j = 0; j < 4; j++)
                acc[i][j] = mfma16(af[i], bfr[j], acc[i][j]);

        __syncthreads();
    }

    #pragma unroll
    for (int j = 0; j < 4; j++) {
        const int n = n0 + wn * 64 + j * 16 + c;
        float b1v = 0.f;
        if (isQ) b1v = rrb[n];
        #pragma unroll
        for (int i = 0; i < 4; i++) {
            const int l0 = m0 + wm * 64 + i * 16 + 4 * g;
            if (!isQ && n >= DM) {
                const int d = n & 63, hh = (n - DM) >> 6;
                const int bb = l0 >> 10, l = l0 & 1023;
                u16x4 o;
                #pragma unroll
                for (int r = 0; r < 4; r++) o[r] = f2bf(acc[i][j][r]);
                *(u16x4*)(vhsT + (((size_t)(bb * NH + hh)) * HD + d) * LEN + l) = o;
            } else {
                #pragma unroll
                for (int r = 0; r < 4; r++) {
                    const int row = l0 + r;
                    const int bb = row >> 10, l = row & 1023;
                    const float v = acc[i][j][r];
                    if (isQ) {
                        size_t idx = (((size_t)(bb * NH + (n >> 6))) * LEN + l) * HD + (n & 63);
                        A1[idx] = f2bf((v + b1v) * QSCALE);
                    } else {
                        const int d = n & 63;
                        const int dsw = (((d >> 3) ^ (l & 7)) << 3) | (d & 7);
                        size_t idx = (((size_t)(bb * NH + (n >> 6))) * LEN + l) * HD + dsw;
                        khs[idx] = f2bf(v);
                    }
                }
            }
        }
    }
}

// ---------------- fused rel-attention, v14: v13 + in-register P via permlane swaps ----------------
// grid (64, 8), 512 threads, 8 waves x 16 q-rows. KVBLK=32.
// P never touches LDS: lane (g,c) holds P[q=c][k in {4g..4g+3, 16+4g..+3}] as 4 bf16-pairs;
// (e0,e2)=pl16swap(pl32swap(d0,d2)), (e1,e3)=pl16swap(pl32swap(d1,d3)) regroups to k=8g..8g+7.
__global__ __launch_bounds__(512, 4) void attn_kernel(
    const u16* __restrict__ A1,
    const u16* __restrict__ khs, const u16* __restrict__ vhsT,
    const u16* __restrict__ rbf, const float* __restrict__ mbias,
    const float* __restrict__ rrb, const float* __restrict__ rwb,
    float* __restrict__ outp)
{
    __shared__ u16 kbuf[2][32][64];      // 8 KB, rows swizzled by key k&7
    __shared__ u16 rbuf[224][64];        // 28 KB rolling ring (slot = j mod 224), key j&7
    __shared__ u16 vbuf[2][4][64][8];    // 8 KB: [buf][kgroup][d][8 keys]
    __shared__ float biasl[1024];        // 4 KB
    __shared__ float gl[8][16][52];      // 26 KB f32 band scores
    // total 75776 B -> 2 blocks/CU

    const int bh = blockIdx.x;
    const int b = bh >> 4, h = bh & 15;
    const int tid = threadIdx.x;
    const int w = tid >> 6, lane = tid & 63, g = lane >> 4, c = lane & 15;
    const int q0 = blockIdx.y * 128, q0w = q0 + w * 16;
    const int lrow8 = lane >> 3, lcol = lane & 7;
    const int kkey = (c + 1) & 7;

    const u16* Kbase = khs + (size_t)bh * LEN * HD;
    const u16* Vp = vhsT + (size_t)bh * HD * LEN;
    float* glw = &gl[w][0][0];

    // q-side fragments; a2f reconstructed from a1f + (rwb - rrb)*QSCALE
    const u16* A1p = A1 + ((size_t)bh * LEN + q0w) * HD;
    bf16x8 a1f[2], a2f[2];
    #pragma unroll
    for (int kf = 0; kf < 2; kf++)
        a1f[kf] = *(const bf16x8*)(A1p + c * HD + kf * 32 + g * 8);
    {
        const float* rrbp = rrb + h * HD;
        const float* rwbp = rwb + h * HD;
        #pragma unroll
        for (int kf = 0; kf < 2; kf++) {
            const int dbase = kf * 32 + g * 8;
            f32x4 rA0 = *(const f32x4*)(rrbp + dbase);
            f32x4 rA1 = *(const f32x4*)(rrbp + dbase + 4);
            f32x4 rB0 = *(const f32x4*)(rwbp + dbase);
            f32x4 rB1 = *(const f32x4*)(rwbp + dbase + 4);
            float a2v[8];
            #pragma unroll
            for (int e = 0; e < 4; e++) {
                a2v[e]     = bf2f((u16)a1f[kf][e])     + (rB0[e] - rA0[e]) * QSCALE;
                a2v[4 + e] = bf2f((u16)a1f[kf][4 + e]) + (rB1[e] - rA1[e]) * QSCALE;
            }
            union { u32 u[4]; bf16x8 v; } cv;
            cv.u[0] = cvt_pk_bf16(a2v[0], a2v[1]);
            cv.u[1] = cvt_pk_bf16(a2v[2], a2v[3]);
            cv.u[2] = cvt_pk_bf16(a2v[4], a2v[5]);
            cv.u[3] = cvt_pk_bf16(a2v[6], a2v[7]);
            a2f[kf] = cv.v;
        }
    }

    // ---- prologue staging: K(0)/V(0) by waves 0-3; bias by waves 4-7; ring 192 rows all waves ----
    const int js0 = LEN - q0 - 128;                  // >= 0, mult of 32
    if (w < 4) {
        gload16(Kbase + (((size_t)(8 * w + lrow8)) << 6) + (lcol << 3), &kbuf[0][8 * w][0]);
        gload16(Vp + ((size_t)lane << 10) + 8 * w, &vbuf[0][w][0][0]);
    } else {
        gload16(mbias + b * LEN + (w - 4) * 256 + lane * 4, &biasl[(w - 4) * 256]);
    }
    #pragma unroll
    for (int i = 0; i < 3; i++) {
        const int row = js0 + 8 * (w + 8 * i);       // groups 0..23 -> rows js0..js0+191
        gload16(rbf + (((size_t)(row + lrow8)) << 6) + (lcol << 3), &rbuf[row % 224][0]);
    }
    __syncthreads();

    // initial R carry: mt0 fragment of tile 0
    bf16x8 RA[2], RB[2];
    int bs = (1009 - q0w) % 224;                     // band base slot for tile 0
    {
        int t = bs + c; if (t >= 224) t -= 224;
        #pragma unroll
        for (int kf = 0; kf < 2; kf++)
            RA[kf] = *(const bf16x8*)&rbuf[t][((4 * kf + g) ^ kkey) * 8];
    }

    const f32x4 fzero = {0.f, 0.f, 0.f, 0.f};
    f32x4 oacc[4];
    #pragma unroll
    for (int dt = 0; dt < 4; dt++) oacc[dt] = fzero;
    float mrow = -3.0e38f, lrow = 0.f;

    auto STEP = [&](int kt, bf16x8 (&Rold)[2], bf16x8 (&Rnew)[2]) {
        const int cur = kt & 1, nb = cur ^ 1;
        const int c0 = kt * 32;

        // ---- staging: K/V one tile ahead (waves 0-3); ring rows TWO tiles ahead (waves 4-7) ----
        if (w < 4) {
            if (kt < 31) {
                const int c0n = c0 + 32;
                gload16(Kbase + (((size_t)(c0n + 8 * w + lrow8)) << 6) + (lcol << 3), &kbuf[nb][8 * w][0]);
                gload16(Vp + ((size_t)lane << 10) + c0n + 8 * w, &vbuf[nb][w][0][0]);
            }
        } else {
            if (kt < 30) {
                const int row0 = js0 + 192 + 32 * kt + 8 * (w - 4);
                gload16(rbf + (((size_t)(row0 + lrow8)) << 6) + (lcol << 3), &rbuf[row0 % 224][0]);
            }
        }

        // ---- K fragments ----
        bf16x8 Kf[2][2];
        #pragma unroll
        for (int ct = 0; ct < 2; ct++)
            #pragma unroll
            for (int kf = 0; kf < 2; kf++)
                Kf[ct][kf] = *(const bf16x8*)&kbuf[cur][16 * ct + c][((4 * kf + g) ^ (c & 7)) * 8];

        // ---- R fragments: mt0 carried; read mt1, mt2 (mt2 -> next carry) ----
        bf16x8 Rf1[2], Rf2[2];
        {
            int t = bs + 16 + c; if (t >= 224) t -= 224;
            #pragma unroll
            for (int kf = 0; kf < 2; kf++)
                Rf1[kf] = *(const bf16x8*)&rbuf[t][((4 * kf + g) ^ kkey) * 8];
        }
        {
            int t = bs + 32 + c; if (t >= 224) t -= 224;
            #pragma unroll
            for (int kf = 0; kf < 2; kf++) {
                Rf2[kf] = *(const bf16x8*)&rbuf[t][((4 * kf + g) ^ kkey) * 8];
                Rnew[kf] = Rf2[kf];
            }
        }

        // ---- AC + band G MFMA cluster ----
        __builtin_amdgcn_s_setprio(1);
        f32x4 s0 = fzero, s1 = fzero;
        s0 = mfma16(Kf[0][0], a1f[0], s0);
        s0 = mfma16(Kf[0][1], a1f[1], s0);
        s1 = mfma16(Kf[1][0], a1f[0], s1);
        s1 = mfma16(Kf[1][1], a1f[1], s1);
        f32x4 g0 = fzero, g1 = fzero, g2 = fzero;
        g0 = mfma16(Rold[0], a2f[0], g0);
        g0 = mfma16(Rold[1], a2f[1], g0);
        *(f32x4*)&glw[c * 52 + 4 * g] = g0;
        g1 = mfma16(Rf1[0], a2f[0], g1);
        g1 = mfma16(Rf1[1], a2f[1], g1);
        *(f32x4*)&glw[c * 52 + 16 + 4 * g] = g1;
        g2 = mfma16(Rf2[0], a2f[0], g2);
        g2 = mfma16(Rf2[1], a2f[1], g2);
        *(f32x4*)&glw[c * 52 + 32 + 4 * g] = g2;
        __builtin_amdgcn_s_setprio(0);

        // ---- gather band + bias: s[ct][r] += G[c][16ct + 4g+r+15-c] ----
        const float* glq = &glw[c * 52];
        f32x4 bb0 = *(const f32x4*)&biasl[c0 + 4 * g];
        f32x4 bb1 = *(const f32x4*)&biasl[c0 + 16 + 4 * g];
        #pragma unroll
        for (int r = 0; r < 4; r++) {
            const int gidx = 4 * g + r + 15 - c;
            s0[r] += glq[gidx] + bb0[r];
            s1[r] += glq[gidx + 16] + bb1[r];
        }

        // ---- online softmax (exp2 domain, defer-max) ----
        float t = fmaxf(fmaxf(fmaxf(s0[0], s0[1]), fmaxf(s0[2], s0[3])),
                        fmaxf(fmaxf(s1[0], s1[1]), fmaxf(s1[2], s1[3])));
        t = fmaxf(t, __shfl_xor(t, 16));
        t = fmaxf(t, __shfl_xor(t, 32));
        if (!__all(t <= mrow + 8.f)) {
            const float mnew = fmaxf(mrow, t);
            const float alpha = exp2f_fast(mrow - mnew);
            mrow = mnew;
            lrow *= alpha;
            #pragma unroll
            for (int dt = 0; dt < 4; dt++)
                #pragma unroll
                for (int r = 0; r < 4; r++) oacc[dt][r] *= alpha;
        }
        float p[8];
        float ps = 0.f;
        #pragma unroll
        for (int r = 0; r < 4; r++) {
            p[r] = exp2f_fast(s0[r] - mrow);
            p[4 + r] = exp2f_fast(s1[r] - mrow);
            ps += p[r] + p[4 + r];
        }
        lrow += ps;

        // ---- P in registers: regroup k-layout via permlane swaps (no LDS) ----
        // d0=(k4g,4g+1) d1=(4g+2,4g+3) d2=(16+4g,+1) d3=(16+4g+2,+3)
        // (e0,e2) = pl16swap(pl32swap(d0,d2));  (e1,e3) = pl16swap(pl32swap(d1,d3))
        u32 x0 = cvt_pk_bf16(p[0], p[1]);
        u32 x1 = cvt_pk_bf16(p[2], p[3]);
        u32 y0 = cvt_pk_bf16(p[4], p[5]);
        u32 y1 = cvt_pk_bf16(p[6], p[7]);
        asm("v_permlane32_swap_b32 %0, %1" : "+v"(x0), "+v"(y0));
        asm("v_permlane16_swap_b32 %0, %1" : "+v"(x0), "+v"(y0));
        asm("v_permlane32_swap_b32 %0, %1" : "+v"(x1), "+v"(y1));
        asm("v_permlane16_swap_b32 %0, %1" : "+v"(x1), "+v"(y1));
        union { u32 u[4]; bf16x8 v; } pbu;
        pbu.u[0] = x0; pbu.u[1] = x1; pbu.u[2] = y0; pbu.u[3] = y1;
        bf16x8 pbr = pbu.v;

        // ---- PV ----
        bf16x8 Vb[4];
        #pragma unroll
        for (int dt = 0; dt < 4; dt++)
            Vb[dt] = *(const bf16x8*)&vbuf[cur][g][16 * dt + c][0];
        __builtin_amdgcn_s_setprio(1);
        #pragma unroll
        for (int dt = 0; dt < 4; dt++)
            oacc[dt] = mfma16(Vb[dt], pbr, oacc[dt]);
        __builtin_amdgcn_s_setprio(0);

        bs += 32; if (bs >= 224) bs -= 224;
        __syncthreads();
    };

    for (int kt2 = 0; kt2 < 16; kt2++) {
        STEP(2 * kt2,     RA, RB);
        STEP(2 * kt2 + 1, RB, RA);
    }

    // ---- epilogue ----
    float sum = lrow;
    sum += __shfl_xor(sum, 16);
    sum += __shfl_xor(sum, 32);
    const float inv = sum > 0.f ? 1.0f / sum : 0.f;
    const int l = q0w + c;
    float* op = outp + ((size_t)b * LEN + l) * DM + h * HD;
    #pragma unroll
    for (int dt = 0; dt < 4; dt++) {
        f32x4 o;
        #pragma unroll
        for (int r = 0; r < 4; r++) o[r] = oacc[dt][r] * inv;
        *(f32x4*)(op + dt * 16 + 4 * g) = o;
    }
}

extern "C" void kernel_launch(void* const* d_in, const int* in_sizes, int n_in,
                              void* d_out, int out_size, void* d_ws, size_t ws_size,
                              hipStream_t stream) {
    const float* q   = (const float*)d_in[0];
    const float* k   = (const float*)d_in[1];
    const int*   msk = (const int*)d_in[2];
    const float* pos = (const float*)d_in[3];
    const float* Wq  = (const float*)d_in[4];
    const float* Wkv = (const float*)d_in[5];
    const float* Wr  = (const float*)d_in[6];
    const float* rrb = (const float*)d_in[7];
    const float* rwb = (const float*)d_in[8];
    float* outp = (float*)d_out;
    char* ws = (char*)d_ws;

    u16* qbf  = (u16*)(ws + 0);              // 8 MB
    u16* kbf  = (u16*)(ws + 8388608);        // 8 MB
    u16* WqT  = (u16*)(ws + 16777216);       // 2 MB
    u16* WkvT = (u16*)(ws + 18874368);       // 4 MB
    u16* rbf  = (u16*)(ws + 23068672);       // 2064*64*2 (swizzled key row&7)
    u16* A1   = (u16*)(ws + 23332864);       // 8 MB (exp2-scaled)
    u16* khs  = (u16*)(ws + 40110080);       // 8 MB (swizzled key l&7)
    u16* vhsT = (u16*)(ws + 48498688);       // 8 MB
    float* mb = (float*)(ws + 56887296);     // 16 KB mask bias

    prep<<<11796, 256, 0, stream>>>(q, k, msk, Wq, Wkv, pos, Wr, qbf, kbf, WqT, WkvT, rbf, mb);
    gemm_all<<<768, 256, 0, stream>>>(qbf, kbf, WqT, WkvT, rrb, A1, khs, vhsT);
    attn_kernel<<<dim3(64, 8), 512, 0, stream>>>(A1, khs, vhsT, rbf, mb, rrb, rwb, outp);
}

// Round 18
// 110.100 us; speedup vs baseline: 1.2576x; 1.0148x over previous
//
#include <hip/hip_runtime.h>

typedef short bf16x8 __attribute__((ext_vector_type(8)));
typedef float f32x4 __attribute__((ext_vector_type(4)));
typedef unsigned short u16;
typedef unsigned short u16x4 __attribute__((ext_vector_type(4)));
typedef unsigned short u16x8 __attribute__((ext_vector_type(8)));
typedef unsigned int u32;

#define NB 4
#define LEN 1024
#define DM 1024
#define NH 16
#define HD 64

// 0.125 (1/sqrt(hd)) * log2(e): projections are emitted in exp2-domain
#define QSCALE 0.18033688011112043f

__device__ __forceinline__ u16 f2bf(float f) {
    union { float f; unsigned u; } v; v.f = f;
    return (u16)((v.u + 0x7fffu + ((v.u >> 16) & 1u)) >> 16);
}

__device__ __forceinline__ float bf2f(u16 x) {
    union { float f; unsigned u; } v; v.u = ((unsigned)x) << 16;
    return v.f;
}

__device__ __forceinline__ float exp2f_fast(float x) {
    float r; asm("v_exp_f32 %0, %1" : "=v"(r) : "v"(x)); return r;
}

__device__ __forceinline__ unsigned cvt_pk_bf16(float a, float b) {
    unsigned r; asm("v_cvt_pk_bf16_f32 %0, %1, %2" : "=v"(r) : "v"(a), "v"(b)); return r;
}

// opaque register copy: prevents regalloc from coalescing the copy with its source
__device__ __forceinline__ float vcopy(float x) {
    float r; asm("v_mov_b32 %0, %1" : "=v"(r) : "v"(x)); return r;
}

// cross-row max reduce (rows = 16-lane groups) entirely on the VALU pipe.
// pl16: x'=[x.r0,y.r0,x.r2,y.r2], y'=[x.r1,y.r1,x.r3,y.r3]
// pl32: x'=[x.lo,y.lo], y'=[x.hi,y.hi]   (semantics validated by v14's pass)
__device__ __forceinline__ float rowmax64(float t) {
    float t1 = vcopy(t);
    asm("v_permlane16_swap_b32 %0, %1" : "+v"(t), "+v"(t1));
    t = fmaxf(t, t1);
    float t2 = vcopy(t);
    asm("v_permlane32_swap_b32 %0, %1" : "+v"(t), "+v"(t2));
    return fmaxf(t, t2);
}

__device__ __forceinline__ float rowsum64(float s) {
    float s1 = vcopy(s);
    asm("v_permlane16_swap_b32 %0, %1" : "+v"(s), "+v"(s1));
    s += s1;
    float s2 = vcopy(s);
    asm("v_permlane32_swap_b32 %0, %1" : "+v"(s), "+v"(s2));
    return s + s2;
}

__device__ __forceinline__ f32x4 mfma16(bf16x8 a, bf16x8 b, f32x4 c) {
    return __builtin_amdgcn_mfma_f32_16x16x32_bf16(a, b, c, 0, 0, 0);
}

// async global->LDS, 16B per lane. LDS base must be wave-uniform (HW adds lane*16).
__device__ __forceinline__ void gload16(const void* g, void* l) {
    __builtin_amdgcn_global_load_lds(
        (const __attribute__((address_space(1))) unsigned int*)g,
        (__attribute__((address_space(3))) unsigned int*)l, 16, 0, 0);
}

// ---------------- fused prep: weight transposes + r-proj + mask + q/k casts ----------------
__global__ void prep(const float* __restrict__ q, const float* __restrict__ k,
                     const int* __restrict__ msk,
                     const float* __restrict__ Wq, const float* __restrict__ Wkv,
                     const float* __restrict__ pos, const float* __restrict__ Wr,
                     u16* __restrict__ qbf, u16* __restrict__ kbf,
                     u16* __restrict__ WqT, u16* __restrict__ WkvT,
                     u16* __restrict__ rbf, float* __restrict__ mb) {
    __shared__ float tile[32][33];
    const int f = blockIdx.x;
    const int tid = threadIdx.x;
    if (f < 3072) {
        // transpose + cast weights: W[K][N] -> WT[N][K] bf16
        const int x = f % 96, y = f / 96;
        const bool isQ = x < 32;
        const float* W = isQ ? Wq : Wkv;
        u16* WT = isQ ? WqT : WkvT;
        const int N = isQ ? 1024 : 2048;
        const int n0 = (isQ ? x : x - 32) * 32;
        const int k0 = y * 32;
        const int tx = tid & 31, ty = tid >> 5;
        #pragma unroll
        for (int j = 0; j < 4; j++) {
            int r = ty + j * 8;
            tile[r][tx] = W[(size_t)(k0 + r) * N + n0 + tx];
        }
        __syncthreads();
        #pragma unroll
        for (int j = 0; j < 4; j++) {
            int r = ty + j * 8;
            WT[(size_t)(n0 + r) * 1024 + k0 + tx] = f2bf(tile[tx][r]);
        }
    } else if (f < 3588) {
        // r = pos_embed @ Wr -> bf16, PRE-SWIZZLED rows (key = row&7), 2064 rows
        int idx = (f - 3072) * 256 + tid;
        if (idx < 2064 * 64) {
            int row = idx >> 6, col = idx & 63;
            float s = 0.f;
            if (row < 2048) {
                #pragma unroll
                for (int kk = 0; kk < 64; kk++) s += pos[row * 64 + kk] * Wr[kk * 64 + col];
            }
            const int csw = (((col >> 3) ^ (row & 7)) << 3) | (col & 7);
            rbf[(row << 6) | csw] = f2bf(s);
        }
    } else if (f < 3604) {
        int i = (f - 3588) * 256 + tid;
        if (i < NB * LEN) mb[i] = msk[i] ? 0.f : -3.0e38f;
    } else {
        // cast q,k fp32 -> bf16 (float4 per thread)
        int idx = (f - 3604) * 256 + tid;
        if (idx < 1048576) {
            float4 v = ((const float4*)q)[idx];
            u16x4 o;
            o[0] = f2bf(v.x); o[1] = f2bf(v.y); o[2] = f2bf(v.z); o[3] = f2bf(v.w);
            ((u16x4*)qbf)[idx] = o;
        } else if (idx < 2097152) {
            int i = idx - 1048576;
            float4 v = ((const float4*)k)[i];
            u16x4 o;
            o[0] = f2bf(v.x); o[1] = f2bf(v.y); o[2] = f2bf(v.z); o[3] = f2bf(v.w);
            ((u16x4*)kbf)[i] = o;
        }
    }
}

// ---------------- unified 128x128 projection GEMM (Q + KV), XCD-chunked ----------------
// Q path writes ONLY A1 (A2 reconstructed in attn from A1 + (rwb-rrb)*QSCALE).
__global__ __launch_bounds__(256) void gemm_all(
    const u16* __restrict__ qbf, const u16* __restrict__ kbf,
    const u16* __restrict__ WqT, const u16* __restrict__ WkvT,
    const float* __restrict__ rrb,
    u16* __restrict__ A1,
    u16* __restrict__ khs, u16* __restrict__ vhsT)
{
    __shared__ u16 as[2][128][32];
    __shared__ u16 bs[2][128][32];

    const int fb = blockIdx.x;
    const int wsw = ((fb & 7) * 96) + (fb >> 3);
    const int bx = wsw % 24;
    const bool isQ = bx < 8;
    const u16* Abf = isQ ? qbf : kbf;
    const u16* BT  = isQ ? WqT : WkvT;
    const int n0 = (isQ ? bx : bx - 8) * 128;
    const int m0 = (wsw / 24) * 128;
    const int tid = threadIdx.x;
    const int w = tid >> 6, lane = tid & 63, g = lane >> 4, c = lane & 15;
    const int wm = w >> 1, wn = w & 1;
    const int srow = lane >> 2, sj = lane & 3;

    const f32x4 fzero = {0.f, 0.f, 0.f, 0.f};
    f32x4 acc[4][4];
    #pragma unroll
    for (int i = 0; i < 4; i++)
        #pragma unroll
        for (int j = 0; j < 4; j++) acc[i][j] = fzero;

    auto STAGE = [&](int buf, int ks) {
        const int k0 = ks * 32;
        #pragma unroll
        for (int i = 0; i < 2; i++) {
            const int rb = w * 32 + i * 16;
            const int rowA = rb + srow;
            gload16(Abf + (size_t)(m0 + rowA) * 1024 + k0 + ((sj ^ (rowA & 3)) << 3),
                    &as[buf][rb][0]);
            gload16(BT + (size_t)(n0 + rowA) * 1024 + k0 + ((sj ^ (rowA & 3)) << 3),
                    &bs[buf][rb][0]);
        }
    };

    STAGE(0, 0);
    __syncthreads();

    for (int ks = 0; ks < 32; ks++) {
        const int cur = ks & 1, nb = cur ^ 1;
        if (ks < 31) STAGE(nb, ks + 1);

        bf16x8 af[4], bfr[4];
        #pragma unroll
        for (int i = 0; i < 4; i++) {
            const int row = wm * 64 + i * 16 + c;
            af[i] = *(const bf16x8*)&as[cur][row][(g ^ (row & 3)) << 3];
        }
        #pragma unroll
        for (int j = 0; j < 4; j++) {
            const int row = wn * 64 + j * 16 + c;
            bfr[j] = *(const bf16x8*)&bs[cur][row][(g ^ (row & 3)) << 3];
        }
        #pragma unroll
        for (int i = 0; i < 4; i++)
            #pragma unroll
            for (int j = 0; j < 4; j++)
                acc[i][j] = mfma16(af[i], bfr[j], acc[i][j]);

        __syncthreads();
    }

    #pragma unroll
    for (int j = 0; j < 4; j++) {
        const int n = n0 + wn * 64 + j * 16 + c;
        float b1v = 0.f;
        if (isQ) b1v = rrb[n];
        #pragma unroll
        for (int i = 0; i < 4; i++) {
            const int l0 = m0 + wm * 64 + i * 16 + 4 * g;
            if (!isQ && n >= DM) {
                const int d = n & 63, hh = (n - DM) >> 6;
                const int bb = l0 >> 10, l = l0 & 1023;
                u16x4 o;
                #pragma unroll
                for (int r = 0; r < 4; r++) o[r] = f2bf(acc[i][j][r]);
                *(u16x4*)(vhsT + (((size_t)(bb * NH + hh)) * HD + d) * LEN + l) = o;
            } else {
                #pragma unroll
                for (int r = 0; r < 4; r++) {
                    const int row = l0 + r;
                    const int bb = row >> 10, l = row & 1023;
                    const float v = acc[i][j][r];
                    if (isQ) {
                        size_t idx = (((size_t)(bb * NH + (n >> 6))) * LEN + l) * HD + (n & 63);
                        A1[idx] = f2bf((v + b1v) * QSCALE);
                    } else {
                        const int d = n & 63;
                        const int dsw = (((d >> 3) ^ (l & 7)) << 3) | (d & 7);
                        size_t idx = (((size_t)(bb * NH + (n >> 6))) * LEN + l) * HD + dsw;
                        khs[idx] = f2bf(v);
                    }
                }
            }
        }
    }
}

// ---------------- fused rel-attention, v16: v14 + VALU-only reduces (aliasing-safe) ----------------
// grid (64, 8), 512 threads, 8 waves x 16 q-rows. KVBLK=32.
__global__ __launch_bounds__(512, 4) void attn_kernel(
    const u16* __restrict__ A1,
    const u16* __restrict__ khs, const u16* __restrict__ vhsT,
    const u16* __restrict__ rbf, const float* __restrict__ mbias,
    const float* __restrict__ rrb, const float* __restrict__ rwb,
    float* __restrict__ outp)
{
    __shared__ u16 kbuf[2][32][64];      // 8 KB, rows swizzled by key k&7
    __shared__ u16 rbuf[224][64];        // 28 KB rolling ring (slot = j mod 224), key j&7
    __shared__ u16 vbuf[2][4][64][8];    // 8 KB: [buf][kgroup][d][8 keys]
    __shared__ float biasl[1024];        // 4 KB
    __shared__ float gl[8][16][52];      // 26 KB f32 band scores
    // total 75776 B -> 2 blocks/CU

    const int bh = blockIdx.x;
    const int b = bh >> 4, h = bh & 15;
    const int tid = threadIdx.x;
    const int w = tid >> 6, lane = tid & 63, g = lane >> 4, c = lane & 15;
    const int q0 = blockIdx.y * 128, q0w = q0 + w * 16;
    const int lrow8 = lane >> 3, lcol = lane & 7;
    const int kkey = (c + 1) & 7;

    const u16* Kbase = khs + (size_t)bh * LEN * HD;
    const u16* Vp = vhsT + (size_t)bh * HD * LEN;
    float* glw = &gl[w][0][0];

    // q-side fragments; a2f reconstructed from a1f + (rwb - rrb)*QSCALE
    const u16* A1p = A1 + ((size_t)bh * LEN + q0w) * HD;
    bf16x8 a1f[2], a2f[2];
    #pragma unroll
    for (int kf = 0; kf < 2; kf++)
        a1f[kf] = *(const bf16x8*)(A1p + c * HD + kf * 32 + g * 8);
    {
        const float* rrbp = rrb + h * HD;
        const float* rwbp = rwb + h * HD;
        #pragma unroll
        for (int kf = 0; kf < 2; kf++) {
            const int dbase = kf * 32 + g * 8;
            f32x4 rA0 = *(const f32x4*)(rrbp + dbase);
            f32x4 rA1 = *(const f32x4*)(rrbp + dbase + 4);
            f32x4 rB0 = *(const f32x4*)(rwbp + dbase);
            f32x4 rB1 = *(const f32x4*)(rwbp + dbase + 4);
            float a2v[8];
            #pragma unroll
            for (int e = 0; e < 4; e++) {
                a2v[e]     = bf2f((u16)a1f[kf][e])     + (rB0[e] - rA0[e]) * QSCALE;
                a2v[4 + e] = bf2f((u16)a1f[kf][4 + e]) + (rB1[e] - rA1[e]) * QSCALE;
            }
            union { u32 u[4]; bf16x8 v; } cv;
            cv.u[0] = cvt_pk_bf16(a2v[0], a2v[1]);
            cv.u[1] = cvt_pk_bf16(a2v[2], a2v[3]);
            cv.u[2] = cvt_pk_bf16(a2v[4], a2v[5]);
            cv.u[3] = cvt_pk_bf16(a2v[6], a2v[7]);
            a2f[kf] = cv.v;
        }
    }

    // ---- prologue staging: K(0)/V(0) by waves 0-3; bias by waves 4-7; ring 192 rows all waves ----
    const int js0 = LEN - q0 - 128;                  // >= 0, mult of 32
    if (w < 4) {
        gload16(Kbase + (((size_t)(8 * w + lrow8)) << 6) + (lcol << 3), &kbuf[0][8 * w][0]);
        gload16(Vp + ((size_t)lane << 10) + 8 * w, &vbuf[0][w][0][0]);
    } else {
        gload16(mbias + b * LEN + (w - 4) * 256 + lane * 4, &biasl[(w - 4) * 256]);
    }
    #pragma unroll
    for (int i = 0; i < 3; i++) {
        const int row = js0 + 8 * (w + 8 * i);       // groups 0..23 -> rows js0..js0+191
        gload16(rbf + (((size_t)(row + lrow8)) << 6) + (lcol << 3), &rbuf[row % 224][0]);
    }
    __syncthreads();

    // initial R carry: mt0 fragment of tile 0
    bf16x8 RA[2], RB[2];
    int bs = (1009 - q0w) % 224;                     // band base slot for tile 0
    {
        int t = bs + c; if (t >= 224) t -= 224;
        #pragma unroll
        for (int kf = 0; kf < 2; kf++)
            RA[kf] = *(const bf16x8*)&rbuf[t][((4 * kf + g) ^ kkey) * 8];
    }

    const f32x4 fzero = {0.f, 0.f, 0.f, 0.f};
    f32x4 oacc[4];
    #pragma unroll
    for (int dt = 0; dt < 4; dt++) oacc[dt] = fzero;
    float mrow = -3.0e38f, lrow = 0.f;

    auto STEP = [&](int kt, bf16x8 (&Rold)[2], bf16x8 (&Rnew)[2]) {
        const int cur = kt & 1, nb = cur ^ 1;
        const int c0 = kt * 32;

        // ---- staging: K/V one tile ahead (waves 0-3); ring rows TWO tiles ahead (waves 4-7) ----
        if (w < 4) {
            if (kt < 31) {
                const int c0n = c0 + 32;
                gload16(Kbase + (((size_t)(c0n + 8 * w + lrow8)) << 6) + (lcol << 3), &kbuf[nb][8 * w][0]);
                gload16(Vp + ((size_t)lane << 10) + c0n + 8 * w, &vbuf[nb][w][0][0]);
            }
        } else {
            if (kt < 30) {
                const int row0 = js0 + 192 + 32 * kt + 8 * (w - 4);
                gload16(rbf + (((size_t)(row0 + lrow8)) << 6) + (lcol << 3), &rbuf[row0 % 224][0]);
            }
        }

        // ---- K fragments ----
        bf16x8 Kf[2][2];
        #pragma unroll
        for (int ct = 0; ct < 2; ct++)
            #pragma unroll
            for (int kf = 0; kf < 2; kf++)
                Kf[ct][kf] = *(const bf16x8*)&kbuf[cur][16 * ct + c][((4 * kf + g) ^ (c & 7)) * 8];

        // ---- R fragments: mt0 carried; read mt1, mt2 (mt2 -> next carry) ----
        bf16x8 Rf1[2], Rf2[2];
        {
            int t = bs + 16 + c; if (t >= 224) t -= 224;
            #pragma unroll
            for (int kf = 0; kf < 2; kf++)
                Rf1[kf] = *(const bf16x8*)&rbuf[t][((4 * kf + g) ^ kkey) * 8];
        }
        {
            int t = bs + 32 + c; if (t >= 224) t -= 224;
            #pragma unroll
            for (int kf = 0; kf < 2; kf++) {
                Rf2[kf] = *(const bf16x8*)&rbuf[t][((4 * kf + g) ^ kkey) * 8];
                Rnew[kf] = Rf2[kf];
            }
        }

        // ---- AC + band G MFMA cluster ----
        __builtin_amdgcn_s_setprio(1);
        f32x4 s0 = fzero, s1 = fzero;
        s0 = mfma16(Kf[0][0], a1f[0], s0);
        s0 = mfma16(Kf[0][1], a1f[1], s0);
        s1 = mfma16(Kf[1][0], a1f[0], s1);
        s1 = mfma16(Kf[1][1], a1f[1], s1);
        f32x4 g0 = fzero, g1 = fzero, g2 = fzero;
        g0 = mfma16(Rold[0], a2f[0], g0);
        g0 = mfma16(Rold[1], a2f[1], g0);
        *(f32x4*)&glw[c * 52 + 4 * g] = g0;
        g1 = mfma16(Rf1[0], a2f[0], g1);
        g1 = mfma16(Rf1[1], a2f[1], g1);
        *(f32x4*)&glw[c * 52 + 16 + 4 * g] = g1;
        g2 = mfma16(Rf2[0], a2f[0], g2);
        g2 = mfma16(Rf2[1], a2f[1], g2);
        *(f32x4*)&glw[c * 52 + 32 + 4 * g] = g2;
        __builtin_amdgcn_s_setprio(0);

        // ---- gather band + bias: s[ct][r] += G[c][16ct + 4g+r+15-c] ----
        const float* glq = &glw[c * 52];
        f32x4 bb0 = *(const f32x4*)&biasl[c0 + 4 * g];
        f32x4 bb1 = *(const f32x4*)&biasl[c0 + 16 + 4 * g];
        #pragma unroll
        for (int r = 0; r < 4; r++) {
            const int gidx = 4 * g + r + 15 - c;
            s0[r] += glq[gidx] + bb0[r];
            s1[r] += glq[gidx + 16] + bb1[r];
        }

        // ---- online softmax (exp2 domain, defer-max; VALU-only reduce) ----
        float t = fmaxf(fmaxf(fmaxf(s0[0], s0[1]), fmaxf(s0[2], s0[3])),
                        fmaxf(fmaxf(s1[0], s1[1]), fmaxf(s1[2], s1[3])));
        t = rowmax64(t);
        if (!__all(t <= mrow + 8.f)) {
            const float mnew = fmaxf(mrow, t);
            const float alpha = exp2f_fast(mrow - mnew);
            mrow = mnew;
            lrow *= alpha;
            #pragma unroll
            for (int dt = 0; dt < 4; dt++)
                #pragma unroll
                for (int r = 0; r < 4; r++) oacc[dt][r] *= alpha;
        }
        float p[8];
        float ps = 0.f;
        #pragma unroll
        for (int r = 0; r < 4; r++) {
            p[r] = exp2f_fast(s0[r] - mrow);
            p[4 + r] = exp2f_fast(s1[r] - mrow);
            ps += p[r] + p[4 + r];
        }
        lrow += ps;

        // ---- P in registers: regroup k-layout via permlane swaps (no LDS) ----
        u32 x0 = cvt_pk_bf16(p[0], p[1]);
        u32 x1 = cvt_pk_bf16(p[2], p[3]);
        u32 y0 = cvt_pk_bf16(p[4], p[5]);
        u32 y1 = cvt_pk_bf16(p[6], p[7]);
        asm("v_permlane32_swap_b32 %0, %1" : "+v"(x0), "+v"(y0));
        asm("v_permlane16_swap_b32 %0, %1" : "+v"(x0), "+v"(y0));
        asm("v_permlane32_swap_b32 %0, %1" : "+v"(x1), "+v"(y1));
        asm("v_permlane16_swap_b32 %0, %1" : "+v"(x1), "+v"(y1));
        union { u32 u[4]; bf16x8 v; } pbu;
        pbu.u[0] = x0; pbu.u[1] = x1; pbu.u[2] = y0; pbu.u[3] = y1;
        bf16x8 pbr = pbu.v;

        // ---- PV ----
        bf16x8 Vb[4];
        #pragma unroll
        for (int dt = 0; dt < 4; dt++)
            Vb[dt] = *(const bf16x8*)&vbuf[cur][g][16 * dt + c][0];
        __builtin_amdgcn_s_setprio(1);
        #pragma unroll
        for (int dt = 0; dt < 4; dt++)
            oacc[dt] = mfma16(Vb[dt], pbr, oacc[dt]);
        __builtin_amdgcn_s_setprio(0);

        bs += 32; if (bs >= 224) bs -= 224;
        __syncthreads();
    };

    for (int kt2 = 0; kt2 < 16; kt2++) {
        STEP(2 * kt2,     RA, RB);
        STEP(2 * kt2 + 1, RB, RA);
    }

    // ---- epilogue ----
    float sum = rowsum64(lrow);
    const float inv = sum > 0.f ? 1.0f / sum : 0.f;
    const int l = q0w + c;
    float* op = outp + ((size_t)b * LEN + l) * DM + h * HD;
    #pragma unroll
    for (int dt = 0; dt < 4; dt++) {
        f32x4 o;
        #pragma unroll
        for (int r = 0; r < 4; r++) o[r] = oacc[dt][r] * inv;
        *(f32x4*)(op + dt * 16 + 4 * g) = o;
    }
}

extern "C" void kernel_launch(void* const* d_in, const int* in_sizes, int n_in,
                              void* d_out, int out_size, void* d_ws, size_t ws_size,
                              hipStream_t stream) {
    const float* q   = (const float*)d_in[0];
    const float* k   = (const float*)d_in[1];
    const int*   msk = (const int*)d_in[2];
    const float* pos = (const float*)d_in[3];
    const float* Wq  = (const float*)d_in[4];
    const float* Wkv = (const float*)d_in[5];
    const float* Wr  = (const float*)d_in[6];
    const float* rrb = (const float*)d_in[7];
    const float* rwb = (const float*)d_in[8];
    float* outp = (float*)d_out;
    char* ws = (char*)d_ws;

    u16* qbf  = (u16*)(ws + 0);              // 8 MB
    u16* kbf  = (u16*)(ws + 8388608);        // 8 MB
    u16* WqT  = (u16*)(ws + 16777216);       // 2 MB
    u16* WkvT = (u16*)(ws + 18874368);       // 4 MB
    u16* rbf  = (u16*)(ws + 23068672);       // 2064*64*2 (swizzled key row&7)
    u16* A1   = (u16*)(ws + 23332864);       // 8 MB (exp2-scaled)
    u16* khs  = (u16*)(ws + 40110080);       // 8 MB (swizzled key l&7)
    u16* vhsT = (u16*)(ws + 48498688);       // 8 MB
    float* mb = (float*)(ws + 56887296);     // 16 KB mask bias

    prep<<<11796, 256, 0, stream>>>(q, k, msk, Wq, Wkv, pos, Wr, qbf, kbf, WqT, WkvT, rbf, mb);
    gemm_all<<<768, 256, 0, stream>>>(qbf, kbf, WqT, WkvT, rrb, A1, khs, vhsT);
    attn_kernel<<<dim3(64, 8), 512, 0, stream>>>(A1, khs, vhsT, rbf, mb, rrb, rwb, outp);
}